// Round 1
// baseline (331.238 us; speedup 1.0000x reference)
//
#include <hip/hip_runtime.h>
#include <hip/hip_bf16.h>

#define HID 1024
#define ADP 256
#define MB  64

typedef short s16x8 __attribute__((ext_vector_type(8)));
typedef float f32x4 __attribute__((ext_vector_type(4)));

__device__ __forceinline__ unsigned short f2bf(float f) {
    union { float f; unsigned int u; } v; v.f = f;
    unsigned int r = v.u + 0x7fffu + ((v.u >> 16) & 1u);   // round-to-nearest-even
    return (unsigned short)(r >> 16);
}

__device__ __forceinline__ float gelu_new_f(float x) {
    float t = 0.7978845608028654f * x * (1.0f + 0.044715f * x * x);
    t = fminf(fmaxf(t, -15.f), 15.f);
    float e = __expf(-2.0f * t);
    float th = (1.0f - e) / (1.0f + e);
    return 0.5f * x * (1.0f + th);
}

// fp32 [R][C] -> bf16 [C][R]
__global__ void transpose_cvt(const float* __restrict__ in, unsigned short* __restrict__ out,
                              int R, int C) {
    __shared__ float t[32][33];
    int r0 = blockIdx.y * 32, c0 = blockIdx.x * 32;
    int tx = threadIdx.x, ty = threadIdx.y;
    #pragma unroll
    for (int j = 0; j < 32; j += 8)
        t[ty + j][tx] = in[(size_t)(r0 + ty + j) * C + c0 + tx];
    __syncthreads();
    #pragma unroll
    for (int j = 0; j < 32; j += 8)
        out[(size_t)(c0 + ty + j) * R + r0 + tx] = f2bf(t[tx][ty + j]);
}

__global__ __launch_bounds__(256, 2)
void adapter_fused(const float* __restrict__ x,
                   const float* __restrict__ lnw, const float* __restrict__ lnb,
                   const float* __restrict__ bdn, const float* __restrict__ bup,
                   const unsigned short* __restrict__ WdT,   // [ADP][HID] bf16
                   const unsigned short* __restrict__ WuT,   // [HID][ADP] bf16
                   float* __restrict__ out)
{
    __shared__ unsigned short a_h[64][264];   // A-chunk (GEMM1) then h (GEMM2)
    __shared__ float ep[4][16][68];           // per-wave epilogue staging
    __shared__ float bdn_s[256];
    __shared__ float bup_s[1024];
    __shared__ float stats[64][2];

    const int tid  = threadIdx.x;
    const int wv   = tid >> 6;
    const int lane = tid & 63;
    const int q    = lane >> 4;
    const int l15  = lane & 15;
    const long row0 = (long)blockIdx.x * MB;

    bdn_s[tid] = bdn[tid];
    ((float4*)bup_s)[tid] = ((const float4*)bup)[tid];

    // ---- Phase 1: LayerNorm statistics (4 threads per row) ----
    {
        int r = tid >> 2, sub = tid & 3;
        const float4* xr = (const float4*)(x + (row0 + r) * HID);
        float s = 0.f, ss = 0.f;
        #pragma unroll 8
        for (int i = 0; i < 64; ++i) {
            float4 v = xr[sub + 4 * i];
            s  += v.x + v.y + v.z + v.w;
            ss += v.x * v.x + v.y * v.y + v.z * v.z + v.w * v.w;
        }
        s += __shfl_xor(s, 1); ss += __shfl_xor(ss, 1);
        s += __shfl_xor(s, 2); ss += __shfl_xor(ss, 2);
        float mean = s * (1.f / HID);
        float var  = ss * (1.f / HID) - mean * mean;
        if (sub == 0) { stats[r][0] = mean; stats[r][1] = rsqrtf(var + 1e-5f); }
    }
    __syncthreads();

    // ---- GEMM1: C1[64x256] = LN(x)[64x1024] * Wd[1024x256], K-chunked ----
    f32x4 c1[4][4];
    #pragma unroll
    for (int a = 0; a < 4; ++a)
        #pragma unroll
        for (int b = 0; b < 4; ++b)
            c1[a][b] = (f32x4){0.f, 0.f, 0.f, 0.f};

    for (int kc = 0; kc < 4; ++kc) {
        {   // stage normalized bf16 chunk into LDS
            int r = tid >> 2, sub = tid & 3;
            float mean = stats[r][0], rstd = stats[r][1];
            const float4* xr = (const float4*)(x + (row0 + r) * HID + kc * 256);
            const float4* wr = (const float4*)(lnw + kc * 256);
            const float4* br = (const float4*)(lnb + kc * 256);
            #pragma unroll
            for (int i = 0; i < 16; ++i) {
                int f4 = sub + 4 * i;
                float4 v = xr[f4], w4 = wr[f4], b4 = br[f4];
                ushort4 o;
                o.x = f2bf((v.x - mean) * rstd * w4.x + b4.x);
                o.y = f2bf((v.y - mean) * rstd * w4.y + b4.y);
                o.z = f2bf((v.z - mean) * rstd * w4.z + b4.z);
                o.w = f2bf((v.w - mean) * rstd * w4.w + b4.w);
                *(ushort4*)&a_h[r][f4 * 4] = o;
            }
        }
        __syncthreads();
        const int nb = wv * 64;
        #pragma unroll
        for (int ks = 0; ks < 8; ++ks) {
            int kof = ks * 32 + q * 8;
            s16x8 af[4], bfr[4];
            #pragma unroll
            for (int mt = 0; mt < 4; ++mt)
                af[mt] = *(const s16x8*)&a_h[mt * 16 + l15][kof];
            #pragma unroll
            for (int nt = 0; nt < 4; ++nt)
                bfr[nt] = *(const s16x8*)&WdT[(size_t)(nb + nt * 16 + l15) * HID + kc * 256 + kof];
            #pragma unroll
            for (int mt = 0; mt < 4; ++mt)
                #pragma unroll
                for (int nt = 0; nt < 4; ++nt)
                    c1[mt][nt] = __builtin_amdgcn_mfma_f32_16x16x32_bf16(af[mt], bfr[nt], c1[mt][nt], 0, 0, 0);
        }
        __syncthreads();
    }

    // ---- gelu(b_down + C1) -> bf16 h, reuse a_h as [64][256] ----
    #pragma unroll
    for (int mt = 0; mt < 4; ++mt)
        #pragma unroll
        for (int nt = 0; nt < 4; ++nt) {
            int n = wv * 64 + nt * 16 + l15;
            float bd = bdn_s[n];
            #pragma unroll
            for (int r = 0; r < 4; ++r) {
                int m = mt * 16 + q * 4 + r;
                a_h[m][n] = f2bf(gelu_new_f(c1[mt][nt][r] + bd));
            }
        }
    __syncthreads();

    // ---- GEMM2: C2[64x1024] = h[64x256] * Wu[256x1024], n-chunked, fused epilogue ----
    for (int ncc = 0; ncc < 4; ++ncc) {
        const int cb = wv * 256 + ncc * 64;
        f32x4 c2[4][4];
        #pragma unroll
        for (int a = 0; a < 4; ++a)
            #pragma unroll
            for (int b = 0; b < 4; ++b)
                c2[a][b] = (f32x4){0.f, 0.f, 0.f, 0.f};
        #pragma unroll
        for (int ks = 0; ks < 8; ++ks) {
            int kof = ks * 32 + q * 8;
            s16x8 af[4], bfr[4];
            #pragma unroll
            for (int mt = 0; mt < 4; ++mt)
                af[mt] = *(const s16x8*)&a_h[mt * 16 + l15][kof];
            #pragma unroll
            for (int nt = 0; nt < 4; ++nt)
                bfr[nt] = *(const s16x8*)&WuT[(size_t)(cb + nt * 16 + l15) * ADP + kof];
            #pragma unroll
            for (int mt = 0; mt < 4; ++mt)
                #pragma unroll
                for (int nt = 0; nt < 4; ++nt)
                    c2[mt][nt] = __builtin_amdgcn_mfma_f32_16x16x32_bf16(af[mt], bfr[nt], c2[mt][nt], 0, 0, 0);
        }
        // epilogue: stage 16x64 tile in LDS -> coalesced float4 out with residual + b_up
        #pragma unroll
        for (int mt = 0; mt < 4; ++mt) {
            #pragma unroll
            for (int nt = 0; nt < 4; ++nt)
                #pragma unroll
                for (int r = 0; r < 4; ++r)
                    ep[wv][q * 4 + r][nt * 16 + l15] = c2[mt][nt][r];
            __builtin_amdgcn_s_waitcnt(0xc07f);   // lgkmcnt(0): wave-local LDS drain
            int rr = lane >> 2, c4 = lane & 3;
            long gm = row0 + mt * 16 + rr;
            const float4* xr  = (const float4*)(x + gm * HID + cb);
            float4* orow      = (float4*)(out + gm * HID + cb);
            #pragma unroll
            for (int i = 0; i < 4; ++i) {
                int f4 = i * 4 + c4;
                float4 v  = *(const float4*)&ep[wv][rr][f4 * 4];
                float4 rs = xr[f4];
                float4 bu = *(const float4*)&bup_s[cb + f4 * 4];
                v.x += rs.x + bu.x; v.y += rs.y + bu.y;
                v.z += rs.z + bu.z; v.w += rs.w + bu.w;
                orow[f4] = v;
            }
            __builtin_amdgcn_s_waitcnt(0xc07f);   // drain reads before next tile overwrites
        }
    }
}

extern "C" void kernel_launch(void* const* d_in, const int* in_sizes, int n_in,
                              void* d_out, int out_size, void* d_ws, size_t ws_size,
                              hipStream_t stream) {
    const float* x   = (const float*)d_in[0];
    const float* lnw = (const float*)d_in[1];
    const float* lnb = (const float*)d_in[2];
    const float* wd  = (const float*)d_in[3];
    const float* bd  = (const float*)d_in[4];
    const float* wu  = (const float*)d_in[5];
    const float* bu  = (const float*)d_in[6];
    float* out = (float*)d_out;

    unsigned short* WdT = (unsigned short*)d_ws;      // [256][1024] bf16
    unsigned short* WuT = WdT + (size_t)HID * ADP;    // [1024][256] bf16

    // w_down: [1024][256] -> WdT [256][1024]
    transpose_cvt<<<dim3(ADP / 32, HID / 32), dim3(32, 8), 0, stream>>>(wd, WdT, HID, ADP);
    // w_up:   [256][1024] -> WuT [1024][256]
    transpose_cvt<<<dim3(HID / 32, ADP / 32), dim3(32, 8), 0, stream>>>(wu, WuT, ADP, HID);

    const int rows = in_sizes[0] / HID;               // 32768
    adapter_fused<<<rows / MB, 256, 0, stream>>>(x, lnw, lnb, bd, bu, WdT, WuT, out);
}